// Round 1
// baseline (40182.922 us; speedup 1.0000x reference)
//
#include <hip/hip_runtime.h>
#include <math.h>

#define DD 64
#define NSWEEP 8

__device__ __forceinline__ int wrap63(int v) { return v >= 63 ? v - 63 : v; }

// Round-robin tournament pairing: stage t in [0,63), pair j in [0,32)
__device__ __forceinline__ void pair_pq(int t, int j, int& p, int& q) {
    p = (j == 0) ? 0 : (1 + wrap63(j - 1 + t));
    q = 1 + wrap63(62 - j + t);
}

__global__ __launch_bounds__(64)
void logeig_jacobi_kernel(const float* __restrict__ X, float* __restrict__ out, int nb) {
    __shared__ float As[DD][DD + 1];
    __shared__ float Vs[DD][DD + 1];
    __shared__ float cs_c[32];
    __shared__ float cs_s[32];
    __shared__ int   pr_p[32];
    __shared__ int   pr_q[32];
    __shared__ float wl[DD];

    const int b = blockIdx.x;
    if (b >= nb) return;
    const int lane = threadIdx.x;

    const float* Xb = X + (size_t)b * DD * DD;

    // Load + symmetrize: As = 0.5*(X + X^T); Vs = I
    for (int r = 0; r < DD; ++r) {
        float a = Xb[r * DD + lane];
        float at = Xb[lane * DD + r];
        As[r][lane] = 0.5f * (a + at);
        Vs[r][lane] = (r == lane) ? 1.0f : 0.0f;
    }
    __syncthreads();

    for (int sw = 0; sw < NSWEEP; ++sw) {
        for (int t = 0; t < 63; ++t) {
            // Phase A: lanes 0..31 compute rotations for the 32 disjoint pairs
            if (lane < 32) {
                int p, q;
                pair_pq(t, lane, p, q);
                float apq = As[p][q];
                float c = 1.0f, s = 0.0f;
                if (fabsf(apq) > 1e-20f) {
                    float app = As[p][p];
                    float aqq = As[q][q];
                    float tau = (aqq - app) / (2.0f * apq);
                    float tt = 1.0f / (fabsf(tau) + sqrtf(1.0f + tau * tau));
                    if (tau < 0.0f) tt = -tt;
                    c = 1.0f / sqrtf(1.0f + tt * tt);
                    s = tt * c;
                }
                cs_c[lane] = c;
                cs_s[lane] = s;
                pr_p[lane] = p;
                pr_q[lane] = q;
            }
            __syncthreads();

            // Phase B: row rotations (A <- J^T A). Lane owns column `lane`.
            #pragma unroll 8
            for (int j = 0; j < 32; ++j) {
                int p = pr_p[j], q = pr_q[j];
                float c = cs_c[j], s = cs_s[j];
                float ap = As[p][lane];
                float aq = As[q][lane];
                As[p][lane] = c * ap - s * aq;
                As[q][lane] = s * ap + c * aq;
            }
            __syncthreads();

            // Phase C: column rotations (A <- A J) and V <- V J. Lane owns row `lane`.
            #pragma unroll 8
            for (int j = 0; j < 32; ++j) {
                int p = pr_p[j], q = pr_q[j];
                float c = cs_c[j], s = cs_s[j];
                float ap = As[lane][p];
                float aq = As[lane][q];
                As[lane][p] = c * ap - s * aq;
                As[lane][q] = s * ap + c * aq;
                float vp = Vs[lane][p];
                float vq = Vs[lane][q];
                Vs[lane][p] = c * vp - s * vq;
                Vs[lane][q] = s * vp + c * vq;
            }
            __syncthreads();
        }
    }

    // Eigenvalues on the diagonal; log with clip
    wl[lane] = logf(fmaxf(As[lane][lane], 1e-7f));
    __syncthreads();

    // vrow[k] = w_k * V[lane][k]  (lane's row of V scaled by log-eigs)
    float vrow[DD];
    #pragma unroll
    for (int k = 0; k < DD; ++k) vrow[k] = Vs[lane][k] * wl[k];

    // out[i][lane] = sum_k V[i][k] * vrow[k]
    float* Ob = out + (size_t)b * DD * DD;
    for (int i = 0; i < DD; ++i) {
        float acc = 0.0f;
        #pragma unroll
        for (int k = 0; k < DD; ++k) acc += Vs[i][k] * vrow[k];
        Ob[i * DD + lane] = acc;
    }
}

extern "C" void kernel_launch(void* const* d_in, const int* in_sizes, int n_in,
                              void* d_out, int out_size, void* d_ws, size_t ws_size,
                              hipStream_t stream) {
    (void)n_in; (void)d_ws; (void)ws_size; (void)out_size;
    const float* X = (const float*)d_in[0];
    float* out = (float*)d_out;
    int nb = in_sizes[0] / (DD * DD);
    dim3 grid(nb);
    dim3 block(DD);
    hipLaunchKernelGGL(logeig_jacobi_kernel, grid, block, 0, stream, X, out, nb);
}

// Round 2
// 22133.037 us; speedup vs baseline: 1.8155x; 1.8155x over previous
//
#include <hip/hip_runtime.h>
#include <math.h>

#define DD 64
#define NSWEEP 8
#define LDA 65

__device__ __forceinline__ int wrap63(int v) { return v >= 63 ? v - 63 : v; }

// Round-robin tournament pairing: stage t in [0,63), pair j in [0,32)
__device__ __forceinline__ void pair_pq(int t, int j, int& p, int& q) {
    p = (j == 0) ? 0 : (1 + wrap63(j - 1 + t));
    q = 1 + wrap63(62 - j + t);
}

__global__ __launch_bounds__(256, 4)
void logeig_jacobi_kernel(const float* __restrict__ X, float* __restrict__ out, int nb) {
    __shared__ float As[DD][LDA];
    __shared__ float Vs[DD][LDA];
    __shared__ float cs_c[32];
    __shared__ float cs_s[32];
    __shared__ int   pr_p[32];
    __shared__ int   pr_q[32];
    __shared__ float wl[DD];

    const int b = blockIdx.x;
    if (b >= nb) return;
    const int tid  = threadIdx.x;
    const int lane = tid & 63;
    const int w    = tid >> 6;   // wave id 0..3

    const float* Xb = X + (size_t)b * DD * DD;

    // Load + symmetrize: As = 0.5*(X + X^T); Vs = I. 16 rows per wave.
    #pragma unroll
    for (int ii = 0; ii < 16; ++ii) {
        int r = w * 16 + ii;
        float a  = Xb[r * DD + lane];
        float at = Xb[lane * DD + r];
        As[r][lane] = 0.5f * (a + at);
        Vs[r][lane] = (r == lane) ? 1.0f : 0.0f;
    }
    __syncthreads();

    for (int sw = 0; sw < NSWEEP; ++sw) {
        for (int t = 0; t < 63; ++t) {
            // Phase A: one thread per pair (every 8th thread) computes (c,s).
            if ((tid & 7) == 0) {
                int j = tid >> 3;   // 0..31
                int p, q;
                pair_pq(t, j, p, q);
                float apq = As[p][q];
                float c = 1.0f, s = 0.0f;
                if (fabsf(apq) > 1e-20f) {
                    float app = As[p][p];
                    float aqq = As[q][q];
                    float tau = (aqq - app) / (2.0f * apq);
                    float tt = 1.0f / (fabsf(tau) + sqrtf(1.0f + tau * tau));
                    if (tau < 0.0f) tt = -tt;
                    c = 1.0f / sqrtf(1.0f + tt * tt);
                    s = tt * c;
                }
                cs_c[j] = c;
                cs_s[j] = s;
                pr_p[j] = p;
                pr_q[j] = q;
            }
            __syncthreads();

            // Phase B: row rotations (A <- J^T A). Thread = (pair j, column lane).
            // Wave w handles pairs 8w..8w+7; lane owns column `lane`.
            #pragma unroll
            for (int i = 0; i < 8; ++i) {
                int j = w * 8 + i;
                int p = pr_p[j], q = pr_q[j];
                float c = cs_c[j], s = cs_s[j];
                float ap = As[p][lane];
                float aq = As[q][lane];
                As[p][lane] = c * ap - s * aq;
                As[q][lane] = s * ap + c * aq;
            }
            __syncthreads();

            // Phase C: column rotations (A <- A J) and (V <- V J).
            // Thread = (pair j, row lane). Wave w handles pairs 8w..8w+7.
            #pragma unroll
            for (int i = 0; i < 8; ++i) {
                int j = w * 8 + i;
                int p = pr_p[j], q = pr_q[j];
                float c = cs_c[j], s = cs_s[j];
                float ap = As[lane][p];
                float aq = As[lane][q];
                As[lane][p] = c * ap - s * aq;
                As[lane][q] = s * ap + c * aq;
                float vp = Vs[lane][p];
                float vq = Vs[lane][q];
                Vs[lane][p] = c * vp - s * vq;
                Vs[lane][q] = s * vp + c * vq;
            }
            __syncthreads();
        }
    }

    // Eigenvalues on the diagonal; log with clip
    if (tid < DD) wl[tid] = logf(fmaxf(As[tid][tid], 1e-7f));
    __syncthreads();

    // out[i][lane] = sum_k V[i][k] * wl[k] * V[lane][k]; 16 rows i per wave.
    float acc[16];
    #pragma unroll
    for (int ii = 0; ii < 16; ++ii) acc[ii] = 0.0f;

    for (int k = 0; k < DD; ++k) {
        float vl = Vs[lane][k] * wl[k];   // per-lane read, bank (lane+k)%32 -> conflict-free
        #pragma unroll
        for (int ii = 0; ii < 16; ++ii) {
            acc[ii] += Vs[w * 16 + ii][k] * vl;   // broadcast read
        }
    }

    float* Ob = out + (size_t)b * DD * DD;
    #pragma unroll
    for (int ii = 0; ii < 16; ++ii) {
        Ob[(size_t)(w * 16 + ii) * DD + lane] = acc[ii];
    }
}

extern "C" void kernel_launch(void* const* d_in, const int* in_sizes, int n_in,
                              void* d_out, int out_size, void* d_ws, size_t ws_size,
                              hipStream_t stream) {
    (void)n_in; (void)d_ws; (void)ws_size; (void)out_size;
    const float* X = (const float*)d_in[0];
    float* out = (float*)d_out;
    int nb = in_sizes[0] / (DD * DD);
    dim3 grid(nb);
    dim3 block(256);
    hipLaunchKernelGGL(logeig_jacobi_kernel, grid, block, 0, stream, X, out, nb);
}

// Round 4
// 16270.927 us; speedup vs baseline: 2.4696x; 1.3603x over previous
//
#include <hip/hip_runtime.h>
#include <math.h>

#define DD 64
#define NSWEEP 7
#define LDA 65

__device__ __forceinline__ int wrap63(int v) { return v >= 63 ? v - 63 : v; }

// Round-robin tournament pairing: stage t in [0,63), pair j in [0,32)
__device__ __forceinline__ void pair_pq(int t, int j, int& p, int& q) {
    p = (j == 0) ? 0 : (1 + wrap63(j - 1 + t));
    q = 1 + wrap63(62 - j + t);
}

__global__ __launch_bounds__(256, 4)
void logeig_jacobi_kernel(const float* __restrict__ X, float* __restrict__ out, int nb) {
    __shared__ float As[DD][LDA];
    __shared__ float Vs[DD][LDA];
    __shared__ float wl[DD];

    const int b = blockIdx.x;
    if (b >= nb) return;
    const int tid  = threadIdx.x;
    const int lane = tid & 63;
    const int w    = tid >> 6;   // wave id 0..3

    const float* Xb = X + (size_t)b * DD * DD;

    // Load + symmetrize: As = 0.5*(X + X^T); Vs = I. 16 rows per wave.
    #pragma unroll
    for (int ii = 0; ii < 16; ++ii) {
        int r = w * 16 + ii;
        float a  = Xb[r * DD + lane];
        float at = Xb[lane * DD + r];
        As[r][lane] = 0.5f * (a + at);
        Vs[r][lane] = (r == lane) ? 1.0f : 0.0f;
    }
    __syncthreads();

    for (int sw = 0; sw < NSWEEP; ++sw) {
        for (int t = 0; t < 63; ++t) {
            // ---- Phase A (wave-local, no barrier needed before B) ----
            // Lanes 0..7 compute (p,q,c,s) for pairs j = w*8 + lane.
            // Corner elements As[p][p],As[p][q],As[q][q] are only written by
            // the pair-owning wave in B (rows p,q) and C (cols p,q), so
            // cross-wave reads here are safe without a barrier.
            int   preg = 0, qreg = 0;
            float cval = 1.0f, sval = 0.0f;
            if (lane < 8) {
                int p, q;
                pair_pq(t, w * 8 + lane, p, q);
                preg = p; qreg = q;
                float apq = As[p][q];
                if (fabsf(apq) > 1e-20f) {
                    float app = As[p][p];
                    float aqq = As[q][q];
                    float tau = (aqq - app) / (2.0f * apq);
                    float tt = 1.0f / (fabsf(tau) + sqrtf(1.0f + tau * tau));
                    if (tau < 0.0f) tt = -tt;
                    float c = 1.0f / sqrtf(1.0f + tt * tt);
                    cval = c;
                    sval = tt * c;
                }
            }

            // Broadcast pair metadata to SGPR-resident arrays (static idx).
            int pp[8], qq[8];
            float cc[8], ss[8];
            #pragma unroll
            for (int i = 0; i < 8; ++i) {
                pp[i] = (int)__builtin_amdgcn_readlane((unsigned)preg, i);
                qq[i] = (int)__builtin_amdgcn_readlane((unsigned)qreg, i);
                cc[i] = __int_as_float(__builtin_amdgcn_readlane(__float_as_int(cval), i));
                ss[i] = __int_as_float(__builtin_amdgcn_readlane(__float_as_int(sval), i));
            }

            // ---- Phase B: row rotations (A <- J^T A). Lane owns column. ----
            #pragma unroll
            for (int i = 0; i < 8; ++i) {
                float ap = As[pp[i]][lane];
                float aq = As[qq[i]][lane];
                As[pp[i]][lane] = cc[i] * ap - ss[i] * aq;
                As[qq[i]][lane] = ss[i] * ap + cc[i] * aq;
            }
            __syncthreads();

            // ---- Phase C: column rotations (A <- A J, V <- V J). Lane owns row. ----
            #pragma unroll
            for (int i = 0; i < 8; ++i) {
                float ap = As[lane][pp[i]];
                float aq = As[lane][qq[i]];
                As[lane][pp[i]] = cc[i] * ap - ss[i] * aq;
                As[lane][qq[i]] = ss[i] * ap + cc[i] * aq;
                float vp = Vs[lane][pp[i]];
                float vq = Vs[lane][qq[i]];
                Vs[lane][pp[i]] = cc[i] * vp - ss[i] * vq;
                Vs[lane][qq[i]] = ss[i] * vp + cc[i] * vq;
            }
            __syncthreads();
        }
    }

    // Eigenvalues on the diagonal; log with clip
    if (tid < DD) wl[tid] = logf(fmaxf(As[tid][tid], 1e-7f));
    __syncthreads();

    // out[i][lane] = sum_k V[i][k] * wl[k] * V[lane][k]; 16 rows i per wave.
    float acc[16];
    #pragma unroll
    for (int ii = 0; ii < 16; ++ii) acc[ii] = 0.0f;

    for (int k = 0; k < DD; ++k) {
        float vl = Vs[lane][k] * wl[k];   // per-lane read, bank (lane+k)%32 -> conflict-free
        #pragma unroll
        for (int ii = 0; ii < 16; ++ii) {
            acc[ii] += Vs[w * 16 + ii][k] * vl;   // broadcast read
        }
    }

    float* Ob = out + (size_t)b * DD * DD;
    #pragma unroll
    for (int ii = 0; ii < 16; ++ii) {
        Ob[(size_t)(w * 16 + ii) * DD + lane] = acc[ii];
    }
}

extern "C" void kernel_launch(void* const* d_in, const int* in_sizes, int n_in,
                              void* d_out, int out_size, void* d_ws, size_t ws_size,
                              hipStream_t stream) {
    (void)n_in; (void)d_ws; (void)ws_size; (void)out_size;
    const float* X = (const float*)d_in[0];
    float* out = (float*)d_out;
    int nb = in_sizes[0] / (DD * DD);
    dim3 grid(nb);
    dim3 block(256);
    hipLaunchKernelGGL(logeig_jacobi_kernel, grid, block, 0, stream, X, out, nb);
}

// Round 7
// 6031.542 us; speedup vs baseline: 6.6621x; 2.6976x over previous
//
#include <hip/hip_runtime.h>
#include <math.h>

#define DD 64
#define NSWEEP 8

__device__ __forceinline__ float rdlane(float v, int l) {
    return __int_as_float(__builtin_amdgcn_readlane(__float_as_int(v), l));
}
__device__ __forceinline__ float bperm(int paddr, float v) {
    return __int_as_float(__builtin_amdgcn_ds_bpermute(paddr, __float_as_int(v)));
}

// Cholesky (Xs = L L^T) + one-sided Jacobi on columns of L, all register-resident.
// L = U Sigma V^T  =>  Xs = U Sigma^2 U^T: lambda_j = ||w_j||^2 after convergence.
// out = sum_j w_j w_j^T * log(clip(lam_j,1e-7)) / lam_j.
__global__ __launch_bounds__(64, 2)
void logeig_chol1s_kernel(const float* __restrict__ X, float* __restrict__ out, int nb) {
    __shared__ float M[DD][DD + 1];   // transpose staging + epilogue buffer
    __shared__ float sc[DD];

    const int b = blockIdx.x;
    if (b >= nb) return;
    const int lane = threadIdx.x & 63;
    const float* Xb = X + (size_t)b * DD * DD;

    // Stage X coalesced, then w = column `lane` of Xs = 0.5*(X + X^T)
    #pragma unroll
    for (int e = 0; e < DD; ++e) M[e][lane] = Xb[e * DD + lane];
    __syncthreads();

    float w[DD];
    #pragma unroll
    for (int e = 0; e < DD; ++e) w[e] = 0.5f * (M[e][lane] + M[lane][e]);

    // ---- In-wave right-looking Cholesky: lane j ends owning column j of L ----
    // k fully unrolled -> all register indices compile-time (no scratch).
    #pragma unroll
    for (int k = 0; k < DD; ++k) {
        const float pivot = rdlane(w[k], k);          // A'[k][k] > 0 (SPD)
        const float rinv  = 1.0f / sqrtf(pivot);
        const float ljk   = w[k] * rinv;              // L[lane][k], valid lane >= k
        const bool  gtk   = (lane > k);
        const bool  eqk   = (lane == k);
        #pragma unroll
        for (int e = k; e < DD; ++e) {
            const float lek = rdlane(w[e], k) * rinv; // L[e][k] (uniform)
            const float upd = fmaf(-lek, ljk, w[e]);  // trailing update
            w[e] = eqk ? lek : (gtk ? upd : w[e]);
        }
    }
    // Zero strict upper part: L[e][lane] = 0 for e < lane
    #pragma unroll
    for (int e = 0; e < DD - 1; ++e)
        w[e] = (e < lane) ? 0.0f : w[e];

    // Initial column norm^2 (maintained incrementally through the sweeps)
    float nown;
    {
        float n0 = 0.f, n1 = 0.f;
        #pragma unroll
        for (int e = 0; e < DD; e += 2) {
            n0 = fmaf(w[e],     w[e],     n0);
            n1 = fmaf(w[e + 1], w[e + 1], n1);
        }
        nown = n0 + n1;
    }

    const int lane4 = lane << 2;

    for (int sw = 0; sw < NSWEEP; ++sw) {
        for (int m = 1; m < DD; ++m) {
            const int paddr = lane4 ^ (m << 2);   // partner*4 (XOR pairing)

            float oth[DD];
            #pragma unroll
            for (int e = 0; e < DD; ++e) oth[e] = bperm(paddr, w[e]);

            // d = w . oth (identical summation order both lanes -> bitwise-equal)
            float d0 = 0.f, d1 = 0.f;
            #pragma unroll
            for (int e = 0; e < DD; e += 2) {
                d0 = fmaf(w[e],     oth[e],     d0);
                d1 = fmaf(w[e + 1], oth[e + 1], d1);
            }
            const float d    = d0 + d1;
            const float noth = bperm(paddr, nown);

            const bool dorot = (d * d > 1e-14f * nown * noth);
            if (__any(dorot)) {
                const bool  islo = (paddr > lane4);   // low lane plays p
                const float app  = islo ? nown : noth;
                const float aqq  = islo ? noth : nown;
                float tau = (aqq - app) * 0.5f / d;
                float t   = 1.0f / (fabsf(tau) + sqrtf(fmaf(tau, tau, 1.0f)));
                t = copysignf(t, tau);
                float c = 1.0f / sqrtf(fmaf(t, t, 1.0f));
                float s = t * c;
                float tsgn = islo ? -t : t;           // nown' = nown -+ t*d
                if (!islo) s = -s;
                if (!dorot) { c = 1.0f; s = 0.0f; tsgn = 0.0f; }
                nown = fmaf(tsgn, d, nown);
                #pragma unroll
                for (int e = 0; e < DD; ++e)
                    w[e] = fmaf(-s, oth[e], c * w[e]);
            }
        }
    }

    // lambda_j = ||w_j||^2 (recomputed fresh for accuracy)
    float n0 = 0.f, n1 = 0.f;
    #pragma unroll
    for (int e = 0; e < DD; e += 2) {
        n0 = fmaf(w[e],     w[e],     n0);
        n1 = fmaf(w[e + 1], w[e + 1], n1);
    }
    const float nn  = n0 + n1;                        // = lambda_j
    const float scl = logf(fmaxf(nn, 1e-7f)) / nn;    // log(clip(lam))/lam

    // Epilogue: out[r][c] = sum_j W[r][j] * scl_j * W[c][j]
    __syncthreads();
    #pragma unroll
    for (int e = 0; e < DD; ++e) M[e][lane] = w[e];
    sc[lane] = scl;
    __syncthreads();

    float vrow[DD];
    #pragma unroll
    for (int j = 0; j < DD; ++j) vrow[j] = M[lane][j] * sc[j];

    float* Ob = out + (size_t)b * DD * DD;
    #pragma unroll 4
    for (int r = 0; r < DD; ++r) {
        float a0 = 0.f, a1 = 0.f;
        #pragma unroll
        for (int j = 0; j < DD; j += 2) {
            a0 = fmaf(M[r][j],     vrow[j],     a0);
            a1 = fmaf(M[r][j + 1], vrow[j + 1], a1);
        }
        Ob[r * DD + lane] = a0 + a1;
    }
}

extern "C" void kernel_launch(void* const* d_in, const int* in_sizes, int n_in,
                              void* d_out, int out_size, void* d_ws, size_t ws_size,
                              hipStream_t stream) {
    (void)n_in; (void)d_ws; (void)ws_size; (void)out_size;
    const float* X = (const float*)d_in[0];
    float* out = (float*)d_out;
    int nb = in_sizes[0] / (DD * DD);
    dim3 grid(nb);
    dim3 block(DD);
    hipLaunchKernelGGL(logeig_chol1s_kernel, grid, block, 0, stream, X, out, nb);
}